// Round 4
// baseline (154.370 us; speedup 1.0000x reference)
//
#include <hip/hip_runtime.h>

typedef _Float16 f16;
typedef f16 f16x8 __attribute__((ext_vector_type(8)));
typedef f16 f16x4 __attribute__((ext_vector_type(4)));
typedef float f32x4 __attribute__((ext_vector_type(4)));

#define MFMA_F16(a, b, c) __builtin_amdgcn_mfma_f32_16x16x32_f16((a), (b), (c), 0, 0, 0)

namespace {
constexpr int SN = 2048;   // sequence length
constexpr int DN = 128;    // head dim
constexpr int KVB = 64;    // kv tile rows
constexpr int NW = 4;      // waves per block
constexpr int QW = 16;     // q rows per wave
constexpr int QB = NW * QW;          // 64 q rows per block
// (1/sqrt(128)) * log2(e): softmax computed in exp2 domain (v_exp_f32 is native exp2)
constexpr float SCALE_L2E = 0.1275213897f;
}

// XOR swizzles (element units; byte-swizzle = <<4)
__device__ __forceinline__ int kidx(int kv, int d)  { return kv * DN  + (d  ^ ((kv & 7) << 3)); }
// sV swizzle: (d ^ (d>>3)) varies across staging lanes AND stays a bijection;
// staging writes + PV reads both sit on the bank floor.
__device__ __forceinline__ int vidx(int d, int kv)  { return d  * KVB + (kv ^ (((d ^ (d >> 3)) & 7) << 3)); }
__device__ __forceinline__ int pidx(int q, int kv)  { return q  * KVB + (kv ^ ((q  & 7) << 3)); }

// 40 KB LDS/block, 4 blocks/CU (160 KB exact), 16 waves/CU = 4 waves/SIMD.
__global__ __launch_bounds__(256, 4)
void mca_kernel(const float* __restrict__ x1, const float* __restrict__ x2,
                float* __restrict__ out)
{
    __shared__ __align__(16) f16 sK[KVB * DN];        // [kv][d]   16 KB
    __shared__ __align__(16) f16 sV[DN * KVB];        // [d][kv]   16 KB (V==K data, transposed)
    __shared__ __align__(16) f16 sP[NW * QW * KVB];   // per-wave [q][kv] 8 KB

    // XCD-chunked swizzle: XCD k processes works [128k, 128k+128) -> consecutive
    // works share (pass,b) KV panels in that XCD's L2.
    const int gid  = blockIdx.x;
    const int work = (gid & 7) * 128 + (gid >> 3);
    const int pass = work >> 9;
    const int b    = (work >> 5) & 15;
    const int q0   = (work & 31) * QB;

    const int t  = threadIdx.x;
    const int w  = t >> 6;
    const int l  = t & 63;
    const int lg = l >> 4;                   // lane group 0..3
    const int ll = l & 15;

    const int rg = t >> 4;                   // staging: rows 4*rg..4*rg+3
    const int cg = t & 15;                   // staging: cols 8*cg..8*cg+7

    f16* sPw = sP + w * (QW * KVB);

    const float* xq  = pass ? x2 : x1;
    const float* xkv = pass ? x1 : x2;
    const float* qb  = xq  + ((size_t)b * SN + q0 + w * QW) * DN;
    const float* kb  = xkv + (size_t)b * SN * DN;

    // ---- Q fragments in registers, pre-scaled by log2e/sqrt(d) ----
    f16x8 qf[4];
    #pragma unroll
    for (int kk = 0; kk < 4; ++kk) {
        const float* p = qb + ll * DN + kk * 32 + lg * 8;
        float4 a0 = *(const float4*)p;
        float4 a1 = *(const float4*)(p + 4);
        f16x8 q;
        q[0] = (f16)(a0.x * SCALE_L2E); q[1] = (f16)(a0.y * SCALE_L2E);
        q[2] = (f16)(a0.z * SCALE_L2E); q[3] = (f16)(a0.w * SCALE_L2E);
        q[4] = (f16)(a1.x * SCALE_L2E); q[5] = (f16)(a1.y * SCALE_L2E);
        q[6] = (f16)(a1.z * SCALE_L2E); q[7] = (f16)(a1.w * SCALE_L2E);
        qf[kk] = q;
    }

    f32x4 oAcc[8];
    #pragma unroll
    for (int n = 0; n < 8; ++n) oAcc[n] = (f32x4){0.f, 0.f, 0.f, 0.f};
    float mrun = -1e30f;
    float lrun = 0.f;

    for (int kv0 = 0; kv0 < SN; kv0 += KVB) {
        __syncthreads();   // previous tile's LDS reads done before overwrite
        // ---- stage KV tile: fp32 global -> fp16 sK (row) + sV (transposed) ----
        {
            const float* src = kb + (size_t)kv0 * DN;
            float hv[4][8];
            #pragma unroll
            for (int rr = 0; rr < 4; ++rr) {
                const float* p = src + (4 * rg + rr) * DN + 8 * cg;
                float4 a0 = *(const float4*)p;
                float4 a1 = *(const float4*)(p + 4);
                hv[rr][0] = a0.x; hv[rr][1] = a0.y; hv[rr][2] = a0.z; hv[rr][3] = a0.w;
                hv[rr][4] = a1.x; hv[rr][5] = a1.y; hv[rr][6] = a1.z; hv[rr][7] = a1.w;
            }
            #pragma unroll
            for (int rr = 0; rr < 4; ++rr) {
                f16x8 kp;
                #pragma unroll
                for (int j = 0; j < 8; ++j) kp[j] = (f16)hv[rr][j];
                *(f16x8*)&sK[kidx(4 * rg + rr, 8 * cg)] = kp;
            }
            #pragma unroll
            for (int i = 0; i < 8; ++i) {
                f16x4 vp;
                #pragma unroll
                for (int rr = 0; rr < 4; ++rr) vp[rr] = (f16)hv[rr][i];
                *(f16x4*)&sV[vidx(8 * cg + i, 4 * rg)] = vp;
            }
        }
        __syncthreads();

        // ---- QK^T swapped: S^T[kv][q] = K · Q^T ----
        f32x4 sacc[4];
        #pragma unroll
        for (int mt = 0; mt < 4; ++mt) sacc[mt] = (f32x4){0.f, 0.f, 0.f, 0.f};
        #pragma unroll
        for (int kk = 0; kk < 4; ++kk) {
            #pragma unroll
            for (int mt = 0; mt < 4; ++mt) {
                f16x8 ka = *(const f16x8*)&sK[kidx(mt * 16 + ll, kk * 32 + lg * 8)];
                sacc[mt] = MFMA_F16(ka, qf[kk], sacc[mt]);
            }
        }

        // ---- online softmax in exp2 domain (row q=ll lives across lg groups) ----
        {
            float tm = sacc[0][0];
            #pragma unroll
            for (int mt = 0; mt < 4; ++mt)
                #pragma unroll
                for (int r = 0; r < 4; ++r) tm = fmaxf(tm, sacc[mt][r]);
            tm = fmaxf(tm, __shfl_xor(tm, 16));
            tm = fmaxf(tm, __shfl_xor(tm, 32));
            float mnew = fmaxf(mrun, tm);
            float corr = exp2f(mrun - mnew);
            float ps = 0.f;
            #pragma unroll
            for (int mt = 0; mt < 4; ++mt) {
                f16x4 pk;
                #pragma unroll
                for (int r = 0; r < 4; ++r) {
                    float pv = exp2f(sacc[mt][r] - mnew);
                    ps += pv;
                    pk[r] = (f16)pv;
                }
                *(f16x4*)&sPw[pidx(ll, mt * 16 + 4 * lg)] = pk;
            }
            ps += __shfl_xor(ps, 16);
            ps += __shfl_xor(ps, 32);
            lrun = lrun * corr + ps;
            mrun = mnew;
            // broadcast rescale factor into the PV accumulator layout
            #pragma unroll
            for (int r = 0; r < 4; ++r) {
                float c2 = __shfl(corr, 4 * lg + r);
                #pragma unroll
                for (int nd = 0; nd < 8; ++nd) oAcc[nd][r] *= c2;
            }
        }

        // ---- PV: O[q][d] += P[q][kv] · V[kv][d] ----
        f16x8 pa[2];
        #pragma unroll
        for (int kc = 0; kc < 2; ++kc)
            pa[kc] = *(const f16x8*)&sPw[pidx(ll, kc * 32 + lg * 8)];
        #pragma unroll
        for (int nd = 0; nd < 8; ++nd) {
            #pragma unroll
            for (int kc = 0; kc < 2; ++kc) {
                f16x8 vb = *(const f16x8*)&sV[vidx(nd * 16 + ll, kc * 32 + lg * 8)];
                oAcc[nd] = MFMA_F16(pa[kc], vb, oAcc[nd]);
            }
        }
    } // kv tiles

    // ---- finalize: O /= l, combine the two passes via atomicAdd ----
    float* ob = out + ((size_t)b * SN + q0 + w * QW) * DN;
    #pragma unroll
    for (int r = 0; r < 4; ++r) {
        float li = __shfl(lrun, 4 * lg + r);
        float inv = 1.0f / li;
        const int row = 4 * lg + r;
        #pragma unroll
        for (int nd = 0; nd < 8; ++nd)
            atomicAdd(&ob[row * DN + nd * 16 + ll], oAcc[nd][r] * inv);
    }
}

extern "C" void kernel_launch(void* const* d_in, const int* in_sizes, int n_in,
                              void* d_out, int out_size, void* d_ws, size_t ws_size,
                              hipStream_t stream) {
    const float* x1 = (const float*)d_in[0];
    const float* x2 = (const float*)d_in[1];
    float* out = (float*)d_out;
    const int B = in_sizes[0] / (SN * DN);   // 16
    hipMemsetAsync(d_out, 0, (size_t)out_size * sizeof(float), stream);
    dim3 grid(2 * B * (SN / QB));            // 1024 blocks = 4 per CU, one pass each
    dim3 block(256);
    hipLaunchKernelGGL(mca_kernel, grid, block, 0, stream, x1, x2, out);
}

// Round 5
// 146.959 us; speedup vs baseline: 1.0504x; 1.0504x over previous
//
#include <hip/hip_runtime.h>

typedef _Float16 f16;
typedef f16 f16x8 __attribute__((ext_vector_type(8)));
typedef f16 f16x4 __attribute__((ext_vector_type(4)));
typedef float f32x4 __attribute__((ext_vector_type(4)));

#define MFMA_F16(a, b, c) __builtin_amdgcn_mfma_f32_16x16x32_f16((a), (b), (c), 0, 0, 0)

namespace {
constexpr int SN = 2048;   // sequence length
constexpr int DN = 128;    // head dim
constexpr int KVB = 64;    // kv tile rows
constexpr int NT = SN / KVB;         // 32 kv tiles
constexpr int NW = 4;      // waves per block
constexpr int QW = 32;     // q rows per wave (K/V LDS reads amortize over QW)
constexpr int QB = NW * QW;          // 128 q rows per block
// (1/sqrt(128)) * log2(e): softmax in exp2 domain (v_exp_f32 is native exp2)
constexpr float SCALE_L2E = 0.1275213897f;
}

// XOR swizzles (element units; byte-swizzle = <<4)
__device__ __forceinline__ int kidx(int kv, int d)  { return kv * DN  + (d  ^ ((kv & 7) << 3)); }
// sV swizzle: (d ^ (d>>3)) varies across staging lanes AND stays a bijection.
__device__ __forceinline__ int vidx(int d, int kv)  { return d  * KVB + (kv ^ (((d ^ (d >> 3)) & 7) << 3)); }
__device__ __forceinline__ int pidx(int q, int kv)  { return q  * KVB + (kv ^ ((q  & 7) << 3)); }

// 80 KB LDS/block, 2 blocks/CU (160 KB exact), 8 waves/CU.
__global__ __launch_bounds__(256, 2)
void mca_kernel(const float* __restrict__ x1, const float* __restrict__ x2,
                float* __restrict__ out)
{
    __shared__ __align__(16) f16 sK[2][KVB * DN];     // [kv][d]   2 x 16 KB (double-buffered)
    __shared__ __align__(16) f16 sV[2][DN * KVB];     // [d][kv]   2 x 16 KB (V==K data, transposed)
    __shared__ __align__(16) f16 sP[NW * QW * KVB];   // per-wave [q][kv] 16 KB

    // XCD-chunked swizzle: XCD k gets works [64k, 64k+64) -> shared (pass,b) KV
    // panels stay in that XCD's L2.
    const int gid  = blockIdx.x;
    const int work = (gid & 7) * 64 + (gid >> 3);
    const int pass = work >> 8;
    const int b    = (work >> 4) & 15;
    const int q0   = (work & 15) * QB;

    const int t  = threadIdx.x;
    const int w  = t >> 6;
    const int l  = t & 63;
    const int lg = l >> 4;                   // lane group 0..3
    const int ll = l & 15;

    const int rg = t >> 4;                   // staging: rows 4*rg..4*rg+3
    const int cg = t & 15;                   // staging: cols 8*cg..8*cg+7

    f16* sPw = sP + w * (QW * KVB);

    const float* xq  = pass ? x2 : x1;
    const float* xkv = pass ? x1 : x2;
    const float* qb  = xq  + ((size_t)b * SN + q0 + w * QW) * DN;
    const float* kb  = xkv + (size_t)b * SN * DN;

    // ---- Q fragments in registers, pre-scaled by log2e/sqrt(d) ----
    f16x8 qf[2][4];
    #pragma unroll
    for (int nq = 0; nq < 2; ++nq)
        #pragma unroll
        for (int kk = 0; kk < 4; ++kk) {
            const float* p = qb + (nq * 16 + ll) * DN + kk * 32 + lg * 8;
            float4 a0 = *(const float4*)p;
            float4 a1 = *(const float4*)(p + 4);
            f16x8 q;
            q[0] = (f16)(a0.x * SCALE_L2E); q[1] = (f16)(a0.y * SCALE_L2E);
            q[2] = (f16)(a0.z * SCALE_L2E); q[3] = (f16)(a0.w * SCALE_L2E);
            q[4] = (f16)(a1.x * SCALE_L2E); q[5] = (f16)(a1.y * SCALE_L2E);
            q[6] = (f16)(a1.z * SCALE_L2E); q[7] = (f16)(a1.w * SCALE_L2E);
            qf[nq][kk] = q;
        }

    // In-flight staging registers (T14 issue-early / write-late)
    float hv[4][8];

    auto LOAD = [&](int tile) {
        const float* src = kb + (size_t)tile * KVB * DN;
        #pragma unroll
        for (int rr = 0; rr < 4; ++rr) {
            const float* p = src + (4 * rg + rr) * DN + 8 * cg;
            float4 a0 = *(const float4*)p;
            float4 a1 = *(const float4*)(p + 4);
            hv[rr][0] = a0.x; hv[rr][1] = a0.y; hv[rr][2] = a0.z; hv[rr][3] = a0.w;
            hv[rr][4] = a1.x; hv[rr][5] = a1.y; hv[rr][6] = a1.z; hv[rr][7] = a1.w;
        }
    };
    auto WRITE = [&](f16* Kb, f16* Vb) {
        #pragma unroll
        for (int rr = 0; rr < 4; ++rr) {
            f16x8 kp;
            #pragma unroll
            for (int j = 0; j < 8; ++j) kp[j] = (f16)hv[rr][j];
            *(f16x8*)&Kb[kidx(4 * rg + rr, 8 * cg)] = kp;
        }
        #pragma unroll
        for (int i = 0; i < 8; ++i) {
            f16x4 vp;
            #pragma unroll
            for (int rr = 0; rr < 4; ++rr) vp[rr] = (f16)hv[rr][i];
            *(f16x4*)&Vb[vidx(8 * cg + i, 4 * rg)] = vp;
        }
    };

    f32x4 oAcc[2][8];
    #pragma unroll
    for (int a = 0; a < 2; ++a)
        #pragma unroll
        for (int n = 0; n < 8; ++n) oAcc[a][n] = (f32x4){0.f, 0.f, 0.f, 0.f};
    float mrun[2] = {-1e30f, -1e30f};
    float lrun[2] = {0.f, 0.f};

    // ---- prologue: stage tile 0 ----
    LOAD(0);
    WRITE(sK[0], sV[0]);
    __syncthreads();

    for (int tile = 0; tile < NT; ++tile) {
        const int cur = tile & 1;
        const f16* Kc = sK[cur];
        const f16* Vc = sV[cur];

        // issue next tile's global loads early — latency hides under QK^T+softmax
        if (tile + 1 < NT) LOAD(tile + 1);

        // ---- QK^T swapped: S^T[kv][q] = K · Q^T ----
        f32x4 sacc[4][2];
        #pragma unroll
        for (int mt = 0; mt < 4; ++mt)
            #pragma unroll
            for (int nq = 0; nq < 2; ++nq) sacc[mt][nq] = (f32x4){0.f, 0.f, 0.f, 0.f};
        #pragma unroll
        for (int kk = 0; kk < 4; ++kk) {
            #pragma unroll
            for (int mt = 0; mt < 4; ++mt) {
                f16x8 ka = *(const f16x8*)&Kc[kidx(mt * 16 + ll, kk * 32 + lg * 8)];
                sacc[mt][0] = MFMA_F16(ka, qf[0][kk], sacc[mt][0]);
                sacc[mt][1] = MFMA_F16(ka, qf[1][kk], sacc[mt][1]);
            }
        }

        // ---- online softmax in exp2 domain (rows across 4-lane groups) ----
        #pragma unroll
        for (int nq = 0; nq < 2; ++nq) {
            const int q = nq * 16 + ll;
            float tm = sacc[0][nq][0];
            #pragma unroll
            for (int mt = 0; mt < 4; ++mt)
                #pragma unroll
                for (int r = 0; r < 4; ++r) tm = fmaxf(tm, sacc[mt][nq][r]);
            tm = fmaxf(tm, __shfl_xor(tm, 16));
            tm = fmaxf(tm, __shfl_xor(tm, 32));
            float mnew = fmaxf(mrun[nq], tm);
            float corr = exp2f(mrun[nq] - mnew);
            float ps = 0.f;
            #pragma unroll
            for (int mt = 0; mt < 4; ++mt) {
                f16x4 pk;
                #pragma unroll
                for (int r = 0; r < 4; ++r) {
                    float pv = exp2f(sacc[mt][nq][r] - mnew);
                    ps += pv;
                    pk[r] = (f16)pv;
                }
                *(f16x4*)&sPw[pidx(q, mt * 16 + 4 * lg)] = pk;
            }
            ps += __shfl_xor(ps, 16);
            ps += __shfl_xor(ps, 32);
            lrun[nq] = lrun[nq] * corr + ps;
            mrun[nq] = mnew;
            // broadcast rescale factor into the PV accumulator layout
            #pragma unroll
            for (int r = 0; r < 4; ++r) {
                float c2 = __shfl(corr, 4 * lg + r);
                #pragma unroll
                for (int nd = 0; nd < 8; ++nd) oAcc[nq][nd][r] *= c2;
            }
        }

        // ---- write next tile into the alternate buffer (vmcnt waits here) ----
        if (tile + 1 < NT) WRITE(sK[cur ^ 1], sV[cur ^ 1]);

        // ---- PV: O[q][d] += P[q][kv] · V[kv][d] ----
        f16x8 pa[2][2];
        #pragma unroll
        for (int mq = 0; mq < 2; ++mq)
            #pragma unroll
            for (int kc = 0; kc < 2; ++kc)
                pa[mq][kc] = *(const f16x8*)&sPw[pidx(mq * 16 + ll, kc * 32 + lg * 8)];
        #pragma unroll
        for (int nd = 0; nd < 8; ++nd) {
            #pragma unroll
            for (int kc = 0; kc < 2; ++kc) {
                f16x8 vb = *(const f16x8*)&Vc[vidx(nd * 16 + ll, kc * 32 + lg * 8)];
                oAcc[0][nd] = MFMA_F16(pa[0][kc], vb, oAcc[0][nd]);
                oAcc[1][nd] = MFMA_F16(pa[1][kc], vb, oAcc[1][nd]);
            }
        }

        // one barrier per tile: everyone done reading cur + writing cur^1
        __syncthreads();
    } // kv tiles

    // ---- finalize: O /= l, combine the two passes via atomicAdd ----
    float* ob = out + ((size_t)b * SN + q0 + w * QW) * DN;
    #pragma unroll
    for (int mq = 0; mq < 2; ++mq)
        #pragma unroll
        for (int r = 0; r < 4; ++r) {
            float li = __shfl(lrun[mq], 4 * lg + r);
            float inv = 1.0f / li;
            const int row = mq * 16 + 4 * lg + r;
            #pragma unroll
            for (int nd = 0; nd < 8; ++nd)
                atomicAdd(&ob[row * DN + nd * 16 + ll], oAcc[mq][nd][r] * inv);
        }
}

extern "C" void kernel_launch(void* const* d_in, const int* in_sizes, int n_in,
                              void* d_out, int out_size, void* d_ws, size_t ws_size,
                              hipStream_t stream) {
    const float* x1 = (const float*)d_in[0];
    const float* x2 = (const float*)d_in[1];
    float* out = (float*)d_out;
    const int B = in_sizes[0] / (SN * DN);   // 16
    hipMemsetAsync(d_out, 0, (size_t)out_size * sizeof(float), stream);
    dim3 grid(2 * B * (SN / QB));            // 512 blocks = 2 per CU, one pass each
    dim3 block(256);
    hipLaunchKernelGGL(mca_kernel, grid, block, 0, stream, x1, x2, out);
}